// Round 7
// baseline (221.962 us; speedup 1.0000x reference)
//
#include <hip/hip_runtime.h>

// FilterInterpolation, round 14.
// out[b,ch,y,x] = mask * sum_{r,c in 5x5} W5[r][c] * img[b,ch, clip(iyT+r), clip(ixL+c)]
//
// R13 post-mortem: occupancy lever falsified (28 waves == 24 waves); MARG
// back to 6. Re-budget via R12 counters: per CU, 128 waves x 50 ds_read_b128
// x 8clk floor = 21us + 9us measured conflicts = ~30us -- HALF the ~60us
// kernel is LDS-pipe time (HBM 16us, VALU 12us). The v4f tap wastes 25% of
// every read on pad.
//
// R14 = R9 with the tile split into a v2f pair-plane (c0,c1) + float plane
// (c2): per tap ds_read_b64(4clk) + ds_read_b32(2clk) = 6clk vs 8clk+42%
// conflict inflation. Same 2 VALU/tap (pk_fma + fma). LDS 24.6->18.5KB ->
// 8 blocks/CU (32-wave cap). Everything else R9-exact: nt stream loads,
// half-split 2px/thread, XCD-chunked swizzle, mul-first W5, nt stores.

#define BB 4
#define HH 544
#define WW 960
#define HW (HH * WW)

#define BX 64          // block pixels in x
#define BY 8           // block pixels in y
#define MARG 6         // tile margin
#define TW (BX + 2 * MARG)   // 76 tile cols
#define TH (BY + 2 * MARG)   // 20 tile rows
#define RS2 (TW + 1)         // 77: row stride (units of one element) in both planes

#define GXB (WW / BX)        // 15
#define GYB (HH / BY)        // 68
#define NWG (GXB * GYB * BB) // 4080
#define CHUNK (NWG / 8)      // 510 blocks per XCD

typedef float v2f __attribute__((ext_vector_type(2)));

__global__ __launch_bounds__(256) void filt_interp_kernel(
    const float* __restrict__ img,   // (B,3,H,W)
    const float* __restrict__ flow,  // (B,2,H,W)
    const float* __restrict__ filt,  // (B,16,H,W)
    float* __restrict__ out)         // (B,3,H,W)
{
    __shared__ v2f  t01[TH * RS2];   // (c0,c1) pairs: 20*77*8 = 12,320 B
    __shared__ float t2[TH * RS2];   // c2 plane:      20*77*4 =  6,160 B
                                     // total 18,480 B -> 8 blocks/CU

    // ---- XCD-chunked bijective swizzle (scalar math on uniform blockIdx) ----
    const int wg  = blockIdx.x;
    const int swz = (wg & 7) * CHUNK + (wg >> 3);
    const int b   = swz / (GXB * GYB);
    const int rem = swz - b * (GXB * GYB);
    const int by  = rem / GXB;
    const int bx  = rem - by * GXB;

    const int tid = threadIdx.x;
    const int x0 = bx * BX;
    const int y0 = by * BY;
    const int tx0 = x0 - MARG;
    const int ty0 = y0 - MARG;

    // ---- stage clipped, split-plane tile ----
    const float* ib0 = img + (size_t)b * 3 * HW;
    const float* ib1 = ib0 + HW;
    const float* ib2 = ib0 + 2 * HW;
    for (int li = tid; li < TH * TW; li += 256) {
        int vr = li / TW;
        int vc = li - vr * TW;
        int gy = min(max(ty0 + vr, 0), HH - 1);
        int gx = min(max(tx0 + vc, 0), WW - 1);
        int gi = gy * WW + gx;
        v2f p; p.x = ib0[gi]; p.y = ib1[gi];
        t01[vr * RS2 + vc] = p;        // ds_write_b64
        t2[vr * RS2 + vc]  = ib2[gi];  // ds_write_b32
    }
    __syncthreads();

    // ---- per-thread: two pixels, half-split (xb and xb+32) ----
    const int xp = tid & 31;
    const int yr = tid >> 5;          // 0..7
    const int xb = x0 + xp;           // k=0 pixel; k=1 pixel is xb+32
    const int y = y0 + yr;
    const int pix = y * WW + xb;

    // Batch all stream loads up-front (independent -> deep MLP).
    // NONTEMPORAL: protects L1/L2 from the 150MB single-use stream (R12).
    const float* fb = flow + (size_t)b * 2 * HW;
    float fxk[2], fyk[2];
    fxk[0] = __builtin_nontemporal_load(fb + pix);
    fxk[1] = __builtin_nontemporal_load(fb + pix + 32);
    fyk[0] = __builtin_nontemporal_load(fb + HW + pix);
    fyk[1] = __builtin_nontemporal_load(fb + HW + pix + 32);

    const float* ftb = filt + (size_t)b * 16 * HW;
    float w3k[2][16];
#pragma unroll
    for (int t = 0; t < 16; t++) {
        w3k[0][t] = __builtin_nontemporal_load(ftb + (size_t)t * HW + pix);
        w3k[1][t] = __builtin_nontemporal_load(ftb + (size_t)t * HW + pix + 32);
    }

    float res[2][3];

#pragma unroll
    for (int k = 0; k < 2; k++) {
        const int xk = xb + 32 * k;
        float fx = fxk[k];
        float fy = fyk[k];
        float x2 = (float)xk + fx;
        float y2 = (float)y + fy;
        bool m = (x2 >= 0.0f) && (y2 >= 0.0f) &&
                 (x2 <= (float)(WW - 1)) && (y2 <= (float)(HH - 1)) &&
                 (fabsf(fx) < (float)WW * 0.5f) && (fabsf(fy) < (float)HH * 0.5f);
        float x2c = fminf(fmaxf(x2, 0.0f), (float)(WW - 1));
        float y2c = fminf(fmaxf(y2, 0.0f), (float)(HH - 1));
        int ix = (int)floorf(x2c);
        int iy = (int)floorf(y2c);
        float alpha = x2c - (float)ix;
        float beta  = y2c - (float)iy;
        int ixL = ix - 1;   // ix + 1 - fs/2
        int iyT = iy - 1;
        float mf = m ? 1.0f : 0.0f;
        float wa = (1.0f - alpha) * (1.0f - beta) * mf;
        float wb = alpha * (1.0f - beta) * mf;
        float wc = (1.0f - alpha) * beta * mf;
        float wd = alpha * beta * mf;

        // Build 5x5 combined weights, mul-first per cell (no zero-init movs).
        float W5[5][5];
#pragma unroll
        for (int j = 0; j < 4; j++) {
#pragma unroll
            for (int i = 0; i < 4; i++) {
                float w3 = w3k[k][j * 4 + i];
                if (j == 0 && i == 0) W5[j][i] = wa * w3;
                else                  W5[j][i] = fmaf(wa, w3, W5[j][i]);
                if (j == 0)           W5[j][i + 1] = wb * w3;
                else                  W5[j][i + 1] = fmaf(wb, w3, W5[j][i + 1]);
                if (i == 0)           W5[j + 1][i] = wc * w3;
                else                  W5[j + 1][i] = fmaf(wc, w3, W5[j + 1][i]);
                W5[j + 1][i + 1] = wd * w3;
            }
        }

        bool ok = (iyT >= ty0) && (iyT + 4 <= ty0 + TH - 1) &&
                  (ixL >= tx0) && (ixL + 4 <= tx0 + TW - 1);

        if (ok) {
            int base = (iyT - ty0) * RS2 + (ixL - tx0);
            v2f a01 = {0.0f, 0.0f};
            float a2 = 0.0f;
#pragma unroll
            for (int r = 0; r < 5; r++) {
#pragma unroll
                for (int c = 0; c < 5; c++) {
                    // ds_read_b64 + ds_read_b32 (6clk) + pk_fma + fma per tap
                    int o = base + r * RS2 + c;
                    float w = W5[r][c];
                    a01 += w * t01[o];
                    a2   = fmaf(w, t2[o], a2);
                }
            }
            res[k][0] = a01.x;
            res[k][1] = a01.y;
            res[k][2] = a2;
        } else {
            // Rare fallback (|flow| tail): direct clipped global gathers.
            float ax = 0.0f, ay = 0.0f, az = 0.0f;
            int cx[5], ry[5];
#pragma unroll
            for (int q = 0; q < 5; q++) {
                cx[q] = min(max(ixL + q, 0), WW - 1);
                ry[q] = min(max(iyT + q, 0), HH - 1);
            }
#pragma unroll
            for (int r = 0; r < 5; r++) {
                int rowb = ry[r] * WW;
#pragma unroll
                for (int c = 0; c < 5; c++) {
                    float w = W5[r][c];
                    int gi = rowb + cx[c];
                    ax = fmaf(w, ib0[gi], ax);
                    ay = fmaf(w, ib1[gi], ay);
                    az = fmaf(w, ib2[gi], az);
                }
            }
            res[k][0] = ax;
            res[k][1] = ay;
            res[k][2] = az;
        }
    }

    // Uniform channel bases for stores -> saddr form; stores stay nt
    // (out is write-once, never re-read in-kernel).
    float* ob = out + (size_t)b * 3 * HW;
#pragma unroll
    for (int ch = 0; ch < 3; ch++) {
        __builtin_nontemporal_store(res[0][ch], ob + (size_t)ch * HW + pix);
        __builtin_nontemporal_store(res[1][ch], ob + (size_t)ch * HW + pix + 32);
    }
}

extern "C" void kernel_launch(void* const* d_in, const int* in_sizes, int n_in,
                              void* d_out, int out_size, void* d_ws, size_t ws_size,
                              hipStream_t stream) {
    const float* img  = (const float*)d_in[0];
    const float* flow = (const float*)d_in[1];
    const float* filt = (const float*)d_in[2];
    float* out = (float*)d_out;

    filt_interp_kernel<<<dim3(NWG), 256, 0, stream>>>(img, flow, filt, out);
}

// Round 8
// 214.707 us; speedup vs baseline: 1.0338x; 1.0338x over previous
//
#include <hip/hip_runtime.h>

// FilterInterpolation, FINAL (revert to round-9 best, 217.8us measured).
// out[b,ch,y,x] = mask * sum_{r,c in 5x5} W5[r][c] * img[b,ch, clip(iyT+r), clip(ixL+c)]
//
// Session conclusion: dur_us = ~158us harness re-poison fills (2x 510MB
// fillBufferAligned at 85% HBM peak -- fixed cost, untouchable) + ~60us
// kernel. The kernel floor is latency-structured and robust: LDS layout
// (R7/R8/R14), VALU cuts (R9), latency reorder (R10), LDS removal (R11,
// +80us -- tile is load-bearing), cache hints (R12, nt required to protect
// L1/L2 from the 150MB single-use stream), and occupancy (R13) were each
// isolated; all null within +/-1% except the two regressions. No pipe
// saturates (HBM 18%, VALU 15%, LDS ~25%); structure is at its practical
// ceiling.
//
// Kernel structure: v4f channel-packed LDS tile (RS4=77 odd stride),
// half-split 2px/thread mapping, XCD-chunked bijective block swizzle,
// saddr-form stream addressing, mul-first W5 build, nt loads + nt stores.

#define BB 4
#define HH 544
#define WW 960
#define HW (HH * WW)

#define BX 64          // block pixels in x
#define BY 8           // block pixels in y
#define MARG 6         // tile margin
#define TW (BX + 2 * MARG)   // 76 tile cols
#define TH (BY + 2 * MARG)   // 20 tile rows
#define RS4 (TW + 1)         // 77 float4s per LDS row (odd -> rows shift bank-group by 5)

#define GXB (WW / BX)        // 15
#define GYB (HH / BY)        // 68
#define NWG (GXB * GYB * BB) // 4080
#define CHUNK (NWG / 8)      // 510 blocks per XCD

typedef float v4f __attribute__((ext_vector_type(4)));

__global__ __launch_bounds__(256) void filt_interp_kernel(
    const float* __restrict__ img,   // (B,3,H,W)
    const float* __restrict__ flow,  // (B,2,H,W)
    const float* __restrict__ filt,  // (B,16,H,W)
    float* __restrict__ out)         // (B,3,H,W)
{
    __shared__ v4f tile[TH * RS4];   // 20*77*16 = 24,640 B -> 6 blocks/CU LDS-cap

    // ---- XCD-chunked bijective swizzle (scalar math on uniform blockIdx) ----
    const int wg  = blockIdx.x;
    const int swz = (wg & 7) * CHUNK + (wg >> 3);
    const int b   = swz / (GXB * GYB);
    const int rem = swz - b * (GXB * GYB);
    const int by  = rem / GXB;
    const int bx  = rem - by * GXB;

    const int tid = threadIdx.x;
    const int x0 = bx * BX;
    const int y0 = by * BY;
    const int tx0 = x0 - MARG;
    const int ty0 = y0 - MARG;

    // ---- stage clipped, channel-packed (float4: c0,c1,c2,0) tile ----
    const float* ib0 = img + (size_t)b * 3 * HW;
    const float* ib1 = ib0 + HW;
    const float* ib2 = ib0 + 2 * HW;
    for (int li = tid; li < TH * TW; li += 256) {
        int vr = li / TW;
        int vc = li - vr * TW;
        int gy = min(max(ty0 + vr, 0), HH - 1);
        int gx = min(max(tx0 + vc, 0), WW - 1);
        int gi = gy * WW + gx;
        v4f t;
        t.x = ib0[gi];
        t.y = ib1[gi];
        t.z = ib2[gi];
        t.w = 0.0f;
        tile[vr * RS4 + vc] = t;     // ds_write_b128, lane-consecutive -> conflict-free
    }
    __syncthreads();

    // ---- per-thread: two pixels, half-split (xb and xb+32) ----
    const int xp = tid & 31;
    const int yr = tid >> 5;          // 0..7
    const int xb = x0 + xp;           // k=0 pixel; k=1 pixel is xb+32
    const int y = y0 + yr;
    const int pix = y * WW + xb;

    // Batch all stream loads up-front (independent -> deep MLP).
    // NONTEMPORAL: protects L1/L2 from the 150MB single-use stream (R12).
    const float* fb = flow + (size_t)b * 2 * HW;
    float fxk[2], fyk[2];
    fxk[0] = __builtin_nontemporal_load(fb + pix);
    fxk[1] = __builtin_nontemporal_load(fb + pix + 32);
    fyk[0] = __builtin_nontemporal_load(fb + HW + pix);
    fyk[1] = __builtin_nontemporal_load(fb + HW + pix + 32);

    const float* ftb = filt + (size_t)b * 16 * HW;
    float w3k[2][16];
#pragma unroll
    for (int t = 0; t < 16; t++) {
        w3k[0][t] = __builtin_nontemporal_load(ftb + (size_t)t * HW + pix);
        w3k[1][t] = __builtin_nontemporal_load(ftb + (size_t)t * HW + pix + 32);
    }

    float res[2][3];

#pragma unroll
    for (int k = 0; k < 2; k++) {
        const int xk = xb + 32 * k;
        float fx = fxk[k];
        float fy = fyk[k];
        float x2 = (float)xk + fx;
        float y2 = (float)y + fy;
        bool m = (x2 >= 0.0f) && (y2 >= 0.0f) &&
                 (x2 <= (float)(WW - 1)) && (y2 <= (float)(HH - 1)) &&
                 (fabsf(fx) < (float)WW * 0.5f) && (fabsf(fy) < (float)HH * 0.5f);
        float x2c = fminf(fmaxf(x2, 0.0f), (float)(WW - 1));
        float y2c = fminf(fmaxf(y2, 0.0f), (float)(HH - 1));
        int ix = (int)floorf(x2c);
        int iy = (int)floorf(y2c);
        float alpha = x2c - (float)ix;
        float beta  = y2c - (float)iy;
        int ixL = ix - 1;   // ix + 1 - fs/2
        int iyT = iy - 1;
        float mf = m ? 1.0f : 0.0f;
        float wa = (1.0f - alpha) * (1.0f - beta) * mf;
        float wb = alpha * (1.0f - beta) * mf;
        float wc = (1.0f - alpha) * beta * mf;
        float wd = alpha * beta * mf;

        // Build 5x5 combined weights, mul-first per cell (no zero-init movs).
        float W5[5][5];
#pragma unroll
        for (int j = 0; j < 4; j++) {
#pragma unroll
            for (int i = 0; i < 4; i++) {
                float w3 = w3k[k][j * 4 + i];
                if (j == 0 && i == 0) W5[j][i] = wa * w3;
                else                  W5[j][i] = fmaf(wa, w3, W5[j][i]);
                if (j == 0)           W5[j][i + 1] = wb * w3;
                else                  W5[j][i + 1] = fmaf(wb, w3, W5[j][i + 1]);
                if (i == 0)           W5[j + 1][i] = wc * w3;
                else                  W5[j + 1][i] = fmaf(wc, w3, W5[j + 1][i]);
                W5[j + 1][i + 1] = wd * w3;
            }
        }

        bool ok = (iyT >= ty0) && (iyT + 4 <= ty0 + TH - 1) &&
                  (ixL >= tx0) && (ixL + 4 <= tx0 + TW - 1);

        if (ok) {
            int base = (iyT - ty0) * RS4 + (ixL - tx0);
            v4f acc = {0.0f, 0.0f, 0.0f, 0.0f};
#pragma unroll
            for (int r = 0; r < 5; r++) {
#pragma unroll
                for (int c = 0; c < 5; c++) {
                    // one ds_read_b128 (offset-imm) + 2x v_pk_fma_f32 per tap
                    acc += W5[r][c] * tile[base + r * RS4 + c];
                }
            }
            res[k][0] = acc.x;
            res[k][1] = acc.y;
            res[k][2] = acc.z;
        } else {
            // Rare fallback (|flow| tail): direct clipped global gathers.
            float ax = 0.0f, ay = 0.0f, az = 0.0f;
            int cx[5], ry[5];
#pragma unroll
            for (int q = 0; q < 5; q++) {
                cx[q] = min(max(ixL + q, 0), WW - 1);
                ry[q] = min(max(iyT + q, 0), HH - 1);
            }
#pragma unroll
            for (int r = 0; r < 5; r++) {
                int rowb = ry[r] * WW;
#pragma unroll
                for (int c = 0; c < 5; c++) {
                    float w = W5[r][c];
                    int gi = rowb + cx[c];
                    ax = fmaf(w, ib0[gi], ax);
                    ay = fmaf(w, ib1[gi], ay);
                    az = fmaf(w, ib2[gi], az);
                }
            }
            res[k][0] = ax;
            res[k][1] = ay;
            res[k][2] = az;
        }
    }

    // Uniform channel bases for stores -> saddr form; stores stay nt
    // (out is write-once, never re-read in-kernel).
    float* ob = out + (size_t)b * 3 * HW;
#pragma unroll
    for (int ch = 0; ch < 3; ch++) {
        __builtin_nontemporal_store(res[0][ch], ob + (size_t)ch * HW + pix);
        __builtin_nontemporal_store(res[1][ch], ob + (size_t)ch * HW + pix + 32);
    }
}

extern "C" void kernel_launch(void* const* d_in, const int* in_sizes, int n_in,
                              void* d_out, int out_size, void* d_ws, size_t ws_size,
                              hipStream_t stream) {
    const float* img  = (const float*)d_in[0];
    const float* flow = (const float*)d_in[1];
    const float* filt = (const float*)d_in[2];
    float* out = (float*)d_out;

    filt_interp_kernel<<<dim3(NWG), 256, 0, stream>>>(img, flow, filt, out);
}